// Round 6
// baseline (301.983 us; speedup 1.0000x reference)
//
#include <hip/hip_runtime.h>

// ---------------------------------------------------------------------------
// Fused MHA forward on MI355X (gfx950), bf16 MFMA path, round 12.
// B=8, N=1024, C=1024, H=16, D=64.  M = B*N = 8192.
// ws (64 MB): [0,16M) xb then ob (xb dead after qkv_gemm)
//             [16,32M) qb then woutb (qb dead after attn)
//             [32,48M) kb  [48,64M) vbT                     (all bf16)
// d_out (32 MB): [0,6M) winb — dead before out_gemm writes d_out.
// NEW vs round 11 (single lever: occupancy 3 -> 4 blocks/CU):
//  * attn lsp: [4][2][16x72] (18.4KB) -> [4][16x64] XOR-swizzled (8KB).
//    Granule swizzle key^((l15&7)<<3) keeps P reads ~2-way bank-free with
//    zero padding. q-groups share lsp sequentially: SM(g0) -> pb_g0 to
//    regs -> SM(g1) overwrites (per-wave scratch, in-order DS pipe).
//    Block LDS 51.2KB -> 40.0KB exactly -> 4 blocks/CU (160KB), 16 waves/CU.
//    launch_bounds(256,4). All else identical to R11 for attribution.
// ---------------------------------------------------------------------------

typedef __bf16 bf16x8 __attribute__((ext_vector_type(8)));
typedef float f32x4 __attribute__((ext_vector_type(4)));
typedef unsigned short us4v __attribute__((ext_vector_type(4)));

#define MFMA16 __builtin_amdgcn_mfma_f32_16x16x32_bf16

__device__ __forceinline__ unsigned short f2bf(float f) {
    return __builtin_bit_cast(unsigned short, (__bf16)f);   // native cvt, RNE
}

__device__ __forceinline__ us4v cvt4(float4 v) {
    us4v r;
    r.x = f2bf(v.x); r.y = f2bf(v.y); r.z = f2bf(v.z); r.w = f2bf(v.w);
    return r;
}

// async global->LDS, 16 B per lane; LDS dest = wave-uniform base + lane*16
__device__ __forceinline__ void gl16(const unsigned short* g, unsigned short* l) {
    __builtin_amdgcn_global_load_lds(
        (const __attribute__((address_space(1))) unsigned*)g,
        (__attribute__((address_space(3))) unsigned*)l, 16, 0, 0);
}

// ---------------------------------------------------------------------------
// Kernel 0: fp32 -> bf16 convert (one float4 per thread)
// ---------------------------------------------------------------------------
__global__ __launch_bounds__(256)
void cvt_bf16(const float* __restrict__ src, unsigned short* __restrict__ dst,
              int n4) {
    const int i = blockIdx.x * 256 + threadIdx.x;
    if (i < n4) {
        float4 v = ((const float4*)src)[i];
        ((us4v*)dst)[i] = cvt4(v);
    }
}

// ---------------------------------------------------------------------------
// Kernel 1: qkv = xb @ winb^T + b_in -> q (x0.125), k in (B,H,N,D) bf16,
//           V written directly transposed as vbT (B,H,D,N) bf16.
// 2-phase: dbuf LDS, stage kt+1 issued before MFMA of kt, one barrier/kt.
// ---------------------------------------------------------------------------
__global__ __launch_bounds__(256, 3)
void qkv_gemm(const unsigned short* __restrict__ xb,   // (8192,1024) bf16
              const unsigned short* __restrict__ wb,   // (3072,1024) bf16
              const float* __restrict__ bias,
              unsigned short* __restrict__ qb, unsigned short* __restrict__ kb,
              unsigned short* __restrict__ vbT)
{
    __shared__ unsigned short lsa[2][128 * 32];
    __shared__ unsigned short lsb[2][128 * 32];
    const int tid  = threadIdx.x;
    const int wave = tid >> 6, lane = tid & 63;
    const int quad = lane >> 4, l15 = lane & 15;
    const int rch = (quad ^ ((l15 >> 1) & 3)) * 8;   // swizzled read chunk
    const int m0 = blockIdx.x * 128, n0 = blockIdx.y * 128;
    const int wm = (wave & 1) * 64, wn = (wave >> 1) * 64;

    const int srow = wave * 32 + (lane >> 2);
    const int scol = ((lane & 3) ^ ((lane >> 3) & 3)) * 8;   // swizzled stage
    const unsigned short* ga = xb + (size_t)(m0 + srow) * 1024 + scol;
    const unsigned short* gb = wb + (size_t)(n0 + srow) * 1024 + scol;
    const int so0 = (wave * 32) * 32;          // stage offsets within a buffer
    const int so1 = (wave * 32 + 16) * 32;

    f32x4 acc[4][4];
#pragma unroll
    for (int i = 0; i < 4; ++i)
#pragma unroll
        for (int j = 0; j < 4; ++j) acc[i][j] = (f32x4){0.f, 0.f, 0.f, 0.f};

    // prologue: stage kt=0 into buf 0
    gl16(ga, &lsa[0][so0]);
    gl16(ga + 16 * 1024, &lsa[0][so1]);
    gl16(gb, &lsb[0][so0]);
    gl16(gb + 16 * 1024, &lsb[0][so1]);
    __syncthreads();

    int buf = 0;
    for (int kt = 0; kt < 32; ++kt) {
        if (kt < 31) {                         // issue next tile's stage early
            const int k0 = (kt + 1) * 32;
            gl16(ga + k0, &lsa[buf ^ 1][so0]);
            gl16(ga + 16 * 1024 + k0, &lsa[buf ^ 1][so1]);
            gl16(gb + k0, &lsb[buf ^ 1][so0]);
            gl16(gb + 16 * 1024 + k0, &lsb[buf ^ 1][so1]);
        }
        const unsigned short* pa = lsa[buf];
        const unsigned short* pb = lsb[buf];
        bf16x8 af[4], bfr[4];
#pragma unroll
        for (int i = 0; i < 4; ++i)
            af[i] = *(const bf16x8*)&pa[(wm + i * 16 + l15) * 32 + rch];
#pragma unroll
        for (int j = 0; j < 4; ++j)
            bfr[j] = *(const bf16x8*)&pb[(wn + j * 16 + l15) * 32 + rch];
#pragma unroll
        for (int i = 0; i < 4; ++i)
#pragma unroll
            for (int j = 0; j < 4; ++j)
                acc[i][j] = MFMA16(af[i], bfr[j], acc[i][j], 0, 0, 0);
        __syncthreads();                       // drain stage + protect buf
        buf ^= 1;
    }

    const int which = n0 >> 10;
    if (which == 2) {
        // V: write transposed (bh, d, seq); (i,r) axis is seq -> pack 4 bf16.
#pragma unroll
        for (int j = 0; j < 4; ++j) {
            const int n = n0 + wn + j * 16 + l15;
            const int c = n & 1023;
            const int h = c >> 6, d = c & 63;
            const float bv = bias[n];
#pragma unroll
            for (int i = 0; i < 4; ++i) {
                const int m = m0 + wm + i * 16 + quad * 4;   // r=0 row
                const int b = m >> 10, s = m & 1023;
                us4v pk;
#pragma unroll
                for (int r = 0; r < 4; ++r) pk[r] = f2bf(acc[i][j][r] + bv);
                *(us4v*)&vbT[(size_t)((b * 16 + h) * 64 + d) * 1024 + s] = pk;
            }
        }
    } else {
        unsigned short* __restrict__ dst = (which == 0) ? qb : kb;
        const float sc = (which == 0) ? 0.125f : 1.0f;   // q / sqrt(64)
#pragma unroll
        for (int j = 0; j < 4; ++j) {
            const int n = n0 + wn + j * 16 + l15;
            const int c = n & 1023;
            const int h = c >> 6, d = c & 63;
            const float bv = bias[n];
#pragma unroll
            for (int i = 0; i < 4; ++i)
#pragma unroll
                for (int r = 0; r < 4; ++r) {
                    const int m = m0 + wm + i * 16 + quad * 4 + r;
                    const int b = m >> 10, s = m & 1023;
                    const float v = (acc[i][j][r] + bv) * sc;
                    dst[(size_t)((b * 16 + h) * 1024 + s) * 64 + d] = f2bf(v);
                }
        }
    }
}

// ---------------------------------------------------------------------------
// Kernel 2: flash attention, swapped-QK^T, 2-phase pipelined, QBLK=128.
//   4 waves x 32 q (2 groups of 16). K/V dbuf in LDS via gl16.
//   P^T scratch: per-wave 16x64 XOR-swizzled (key ^ ((l15&7)<<3)), shared
//   sequentially by the two q-groups (pb_g0 captured to regs before g1
//   overwrites). Block LDS = 40 KB exactly -> 4 blocks/CU, 16 waves/CU.
//   S^T = MFMA(K,Q): lane (quad,l15) holds S[q=l15][key=quad*4+r].
// Grid 1024, XCD-swizzled (16 bh per XCD).
// ---------------------------------------------------------------------------
__global__ __launch_bounds__(256, 4)
void attn_kernel(const unsigned short* __restrict__ qb,
                 const unsigned short* __restrict__ kb,
                 const unsigned short* __restrict__ vbT,  // (bh, d, n)
                 const float* __restrict__ mask,
                 unsigned short* __restrict__ ob)   // (B, N, C) bf16
{
    __shared__ unsigned short lsk[2][2][64 * 32];     // [buf][d-half][seq*32]
    __shared__ unsigned short lsv[2][2][64 * 32];     // [buf][key-half][d*32]
    __shared__ unsigned short lsp[4][16 * 64];        // per-wave P^T, swizzled
    const int tid  = threadIdx.x;
    const int wave = tid >> 6, lane = tid & 63;
    const int quad = lane >> 4, l15 = lane & 15;
    const int rch = (quad ^ ((l15 >> 1) & 3)) * 8;   // swizzled read chunk
    const int swz = (l15 & 7) << 3;                  // P granule swizzle
    // XCD swizzle: 1024 blocks, XCD (p&7) owns lg in [ (p&7)*128, +128 )
    // = bh in [ (p&7)*16, +16 )  (K/V working set ~4 MB per L2)
    const int p  = blockIdx.x;
    const int lg = (p & 7) * 128 + (p >> 3);
    const int bh = lg >> 3;                      // b*16+h
    const int q0 = (lg & 7) * 128;
    const int b = bh >> 4, h = bh & 15;

    const unsigned short* __restrict__ kbase = kb + (size_t)bh * 65536;
    const unsigned short* __restrict__ vtb  = vbT + (size_t)bh * 65536;

    const int scol = ((lane & 3) ^ ((lane >> 3) & 3)) * 8;   // swizzled stage
    const unsigned short* gk = kbase + (size_t)(wave * 16 + (lane >> 2)) * 64
                                     + scol;
    const unsigned short* gv = vtb + (size_t)(wave * 16 + (lane >> 2)) * 1024
                                   + scol;
    const int so = (wave * 16) * 32;             // stage offset within a half

    // Q fragments, 2 groups (B-operand: n = l15 = q, k = quad*8+j = d)
    bf16x8 bq[2][2];
#pragma unroll
    for (int g = 0; g < 2; ++g) {
        const unsigned short* qrow =
            qb + (size_t)(bh * 1024 + q0 + wave * 32 + g * 16 + l15) * 64;
        bq[g][0] = *(const bf16x8*)(qrow + quad * 8);
        bq[g][1] = *(const bf16x8*)(qrow + 32 + quad * 8);
    }

    float lsum[2] = {0.f, 0.f};
    f32x4 oacc[2][4];              // [grp][nt]: O[q=l15][d=nt*16+quad*4+r]
#pragma unroll
    for (int g = 0; g < 2; ++g)
#pragma unroll
        for (int nt = 0; nt < 4; ++nt) oacc[g][nt] = (f32x4){0.f, 0.f, 0.f, 0.f};

    const float* __restrict__ mrow0 =
        mask + (size_t)(q0 + wave * 32 + l15) * 1024;
    const float* __restrict__ mrow1 = mrow0 + 16 * 1024;
    unsigned short* lp = lsp[wave];

    // prologue: stage tile 0 into buf 0
    gl16(gk, &lsk[0][0][so]);
    gl16(gk + 32, &lsk[0][1][so]);
    gl16(gv, &lsv[0][0][so]);
    gl16(gv + 32, &lsv[0][1][so]);
    __syncthreads();

    int buf = 0;
    for (int kt = 0; kt < 16; ++kt) {
        // mask for CURRENT tile: issued FIRST so the softmax wait retires
        // these without draining the younger gl16 prefetch
        float4 mv[2][4];
#pragma unroll
        for (int nt = 0; nt < 4; ++nt) {
            mv[0][nt] = *(const float4*)&mrow0[kt * 64 + nt * 16 + quad * 4];
            mv[1][nt] = *(const float4*)&mrow1[kt * 64 + nt * 16 + quad * 4];
        }
        __builtin_amdgcn_sched_barrier(0);     // keep mask loads oldest
        if (kt < 15) {                         // stage next tile early
            gl16(gk + (size_t)(kt + 1) * 4096, &lsk[buf ^ 1][0][so]);
            gl16(gk + (size_t)(kt + 1) * 4096 + 32, &lsk[buf ^ 1][1][so]);
            gl16(gv + (size_t)(kt + 1) * 64, &lsv[buf ^ 1][0][so]);
            gl16(gv + (size_t)(kt + 1) * 64 + 32, &lsv[buf ^ 1][1][so]);
        }

        // S^T = K Q^T  (C-layout: row=key=quad*4+r, col=q=l15), both groups
        const unsigned short* rk0 = lsk[buf][0];
        const unsigned short* rk1 = lsk[buf][1];
        f32x4 s[2][4];
        __builtin_amdgcn_s_setprio(1);
#pragma unroll
        for (int nt = 0; nt < 4; ++nt) {
            const bf16x8 k0 = *(const bf16x8*)&rk0[(nt * 16 + l15) * 32 + rch];
            const bf16x8 k1 = *(const bf16x8*)&rk1[(nt * 16 + l15) * 32 + rch];
            s[0][nt] = MFMA16(k0, bq[0][0], (f32x4){0.f, 0.f, 0.f, 0.f}, 0, 0, 0);
            s[0][nt] = MFMA16(k1, bq[0][1], s[0][nt], 0, 0, 0);
            s[1][nt] = MFMA16(k0, bq[1][0], (f32x4){0.f, 0.f, 0.f, 0.f}, 0, 0, 0);
            s[1][nt] = MFMA16(k1, bq[1][1], s[1][nt], 0, 0, 0);
        }
        __builtin_amdgcn_s_setprio(0);

        // SM g0: p = exp(s + mask) -> swizzled lsp; capture pb_g0 to regs
#pragma unroll
        for (int nt = 0; nt < 4; ++nt) {
            us4v pk;
#pragma unroll
            for (int r = 0; r < 4; ++r) {
                const float pe =
                    __expf(s[0][nt][r] + ((const float*)&mv[0][nt])[r]);
                lsum[0] += pe;
                pk[r] = f2bf(pe);
            }
            *(us4v*)&lp[(l15 << 6) + ((nt * 16 + quad * 4) ^ swz)] = pk;
        }
        bf16x8 pb0[2];
        pb0[0] = *(const bf16x8*)&lp[(l15 << 6) + ((quad * 8) ^ swz)];
        pb0[1] = *(const bf16x8*)&lp[(l15 << 6) + ((32 + quad * 8) ^ swz)];

        // SM g1: overwrites the same per-wave lsp (after pb0 reads)
#pragma unroll
        for (int nt = 0; nt < 4; ++nt) {
            us4v pk;
#pragma unroll
            for (int r = 0; r < 4; ++r) {
                const float pe =
                    __expf(s[1][nt][r] + ((const float*)&mv[1][nt])[r]);
                lsum[1] += pe;
                pk[r] = f2bf(pe);
            }
            *(us4v*)&lp[(l15 << 6) + ((nt * 16 + quad * 4) ^ swz)] = pk;
        }
        bf16x8 pb1[2];
        pb1[0] = *(const bf16x8*)&lp[(l15 << 6) + ((quad * 8) ^ swz)];
        pb1[1] = *(const bf16x8*)&lp[(l15 << 6) + ((32 + quad * 8) ^ swz)];

        // O += P V via O = (V^T as A) x (P^T as B): C row=d, col=q
        const unsigned short* rv0 = lsv[buf][0];
        const unsigned short* rv1 = lsv[buf][1];
        __builtin_amdgcn_s_setprio(1);
#pragma unroll
        for (int nt = 0; nt < 4; ++nt) {
            const bf16x8 v0 = *(const bf16x8*)&rv0[(nt * 16 + l15) * 32 + rch];
            const bf16x8 v1 = *(const bf16x8*)&rv1[(nt * 16 + l15) * 32 + rch];
            oacc[0][nt] = MFMA16(v0, pb0[0], oacc[0][nt], 0, 0, 0);
            oacc[0][nt] = MFMA16(v1, pb0[1], oacc[0][nt], 0, 0, 0);
            oacc[1][nt] = MFMA16(v0, pb1[0], oacc[1][nt], 0, 0, 0);
            oacc[1][nt] = MFMA16(v1, pb1[1], oacc[1][nt], 0, 0, 0);
        }
        __builtin_amdgcn_s_setprio(0);

        __syncthreads();                       // drain stage + protect bufs
        buf ^= 1;
    }

    // row-sum: partial sums per-quad; reduce across lane bits 4,5
#pragma unroll
    for (int g = 0; g < 2; ++g) {
        lsum[g] += __shfl_xor(lsum[g], 16, 64);
        lsum[g] += __shfl_xor(lsum[g], 32, 64);
    }
#pragma unroll
    for (int g = 0; g < 2; ++g) {
        const float inv = 1.0f / lsum[g];
        unsigned short* orow =
            ob + (size_t)(b * 1024 + q0 + wave * 32 + g * 16 + l15) * 1024
               + h * 64;
#pragma unroll
        for (int nt = 0; nt < 4; ++nt) {
            us4v o;
#pragma unroll
            for (int r = 0; r < 4; ++r) o[r] = f2bf(oacc[g][nt][r] * inv);
            *(us4v*)&orow[nt * 16 + quad * 4] = o;
        }
    }
}

// ---------------------------------------------------------------------------
// Kernel 3: out = ob(bf16) @ woutb^T + out_b, fp32 to d_out.
// 2-phase: dbuf LDS, stage kt+1 before MFMA of kt, one barrier/kt.
// ---------------------------------------------------------------------------
__global__ __launch_bounds__(256, 3)
void out_gemm(const unsigned short* __restrict__ a,   // (8192,1024) bf16
              const unsigned short* __restrict__ wb,  // (1024,1024) bf16
              const float* __restrict__ bias, float* __restrict__ out)
{
    __shared__ unsigned short lsa[2][128 * 32];
    __shared__ unsigned short lsb[2][128 * 32];
    const int tid  = threadIdx.x;
    const int wave = tid >> 6, lane = tid & 63;
    const int quad = lane >> 4, l15 = lane & 15;
    const int rch = (quad ^ ((l15 >> 1) & 3)) * 8;
    const int m0 = blockIdx.x * 128, n0 = blockIdx.y * 128;
    const int wm = (wave & 1) * 64, wn = (wave >> 1) * 64;

    const int srow = wave * 32 + (lane >> 2);
    const int scol = ((lane & 3) ^ ((lane >> 3) & 3)) * 8;
    const unsigned short* ga = a + (size_t)(m0 + srow) * 1024 + scol;
    const unsigned short* gb = wb + (size_t)(n0 + srow) * 1024 + scol;
    const int so0 = (wave * 32) * 32;
    const int so1 = (wave * 32 + 16) * 32;

    f32x4 acc[4][4];
#pragma unroll
    for (int i = 0; i < 4; ++i)
#pragma unroll
        for (int j = 0; j < 4; ++j) acc[i][j] = (f32x4){0.f, 0.f, 0.f, 0.f};

    gl16(ga, &lsa[0][so0]);
    gl16(ga + 16 * 1024, &lsa[0][so1]);
    gl16(gb, &lsb[0][so0]);
    gl16(gb + 16 * 1024, &lsb[0][so1]);
    __syncthreads();

    int buf = 0;
    for (int kt = 0; kt < 32; ++kt) {
        if (kt < 31) {
            const int k0 = (kt + 1) * 32;
            gl16(ga + k0, &lsa[buf ^ 1][so0]);
            gl16(ga + 16 * 1024 + k0, &lsa[buf ^ 1][so1]);
            gl16(gb + k0, &lsb[buf ^ 1][so0]);
            gl16(gb + 16 * 1024 + k0, &lsb[buf ^ 1][so1]);
        }
        const unsigned short* pa = lsa[buf];
        const unsigned short* pb = lsb[buf];
        bf16x8 af[4], bfr[4];
#pragma unroll
        for (int i = 0; i < 4; ++i)
            af[i] = *(const bf16x8*)&pa[(wm + i * 16 + l15) * 32 + rch];
#pragma unroll
        for (int j = 0; j < 4; ++j)
            bfr[j] = *(const bf16x8*)&pb[(wn + j * 16 + l15) * 32 + rch];
#pragma unroll
        for (int i = 0; i < 4; ++i)
#pragma unroll
            for (int j = 0; j < 4; ++j)
                acc[i][j] = MFMA16(af[i], bfr[j], acc[i][j], 0, 0, 0);
        __syncthreads();
        buf ^= 1;
    }

#pragma unroll
    for (int j = 0; j < 4; ++j) {
        const int n = n0 + wn + j * 16 + l15;
        const float bv = bias[n];
#pragma unroll
        for (int i = 0; i < 4; ++i)
#pragma unroll
            for (int r = 0; r < 4; ++r) {
                const int m = m0 + wm + i * 16 + quad * 4 + r;
                out[(size_t)m * 1024 + n] = acc[i][j][r] + bv;
            }
    }
}

// ---------------------------------------------------------------------------
extern "C" void kernel_launch(void* const* d_in, const int* in_sizes, int n_in,
                              void* d_out, int out_size, void* d_ws, size_t ws_size,
                              hipStream_t stream) {
    const float* x    = (const float*)d_in[0];   // (8, 1024, 1024)
    const float* mask = (const float*)d_in[1];   // (1024, 1024)
    const float* win  = (const float*)d_in[2];   // (3072, 1024)
    const float* bin  = (const float*)d_in[3];   // (3072)
    const float* wout = (const float*)d_in[4];   // (1024, 1024)
    const float* bout = (const float*)d_in[5];   // (1024)
    float* out = (float*)d_out;                  // (8, 1024, 1024)

    char* ws = (char*)d_ws;
    unsigned short* xb = (unsigned short*)(ws);
    unsigned short* ob = (unsigned short*)(ws);                       // overlays xb
    unsigned short* qb = (unsigned short*)(ws + (size_t)(16 << 20));
    unsigned short* kb = (unsigned short*)(ws + (size_t)(32 << 20));
    unsigned short* vbT = (unsigned short*)(ws + (size_t)(48 << 20));
    unsigned short* winb  = (unsigned short*)d_out;                   // [0, 6M)
    unsigned short* woutb = qb;   // overlays qb AFTER attn (qb dead) — no race

    cvt_bf16<<<dim3(8192), 256, 0, stream>>>(x, xb, 8 * 1024 * 1024 / 4);
    cvt_bf16<<<dim3(3072), 256, 0, stream>>>(win, winb, 3 * 1024 * 1024 / 4);
    qkv_gemm<<<dim3(64, 24), 256, 0, stream>>>(xb, winb, bin, qb, kb, vbT);
    attn_kernel<<<dim3(1024), 256, 0, stream>>>(qb, kb, vbT, mask, ob);
    cvt_bf16<<<dim3(1024), 256, 0, stream>>>(wout, woutb, 1024 * 1024 / 4);
    out_gemm<<<dim3(64, 8), 256, 0, stream>>>(ob, woutb, bout, out);
}

// Round 7
// 277.336 us; speedup vs baseline: 1.0889x; 1.0889x over previous
//
#include <hip/hip_runtime.h>

// ---------------------------------------------------------------------------
// Fused MHA forward on MI355X (gfx950), bf16 MFMA path, round 13.
// B=8, N=1024, C=1024, H=16, D=64.  M = B*N = 8192.
// ws (64 MB): [0,16M) xb then ob; [16,32M) qb then woutb; [32,48M) kb;
//             [48,64M) vbT.   d_out: [0,6M) winb (dead before out_gemm).
// NEW vs round 12 (counted-vmcnt schedule, T4):
//  * attn: lsp back to PARALLEL per-group buffers (R12's 117us came from
//    sequential lsp serialization) with swizzled 64-col addressing (16KB).
//    Mask in REGISTER dbuf, issued after the t+1 gl16s (sched_barrier pins
//    order). End-of-iter: lgkmcnt(0) -> s_waitcnt vmcnt(8) -> RAW s_barrier:
//    gl16(t+1) lands, mask(t+1) rides across the barrier. vmcnt never 0.
//  * qkv/out_gemm: triple-buffered LDS, prefetch distance 2, top-of-iter
//    vmcnt(8)+raw barrier (stage has 2 iters to land), end lgkmcnt(0)+bar.
// ---------------------------------------------------------------------------

typedef __bf16 bf16x8 __attribute__((ext_vector_type(8)));
typedef float f32x4 __attribute__((ext_vector_type(4)));
typedef unsigned short us4v __attribute__((ext_vector_type(4)));

#define MFMA16 __builtin_amdgcn_mfma_f32_16x16x32_bf16

__device__ __forceinline__ unsigned short f2bf(float f) {
    return __builtin_bit_cast(unsigned short, (__bf16)f);   // native cvt, RNE
}

__device__ __forceinline__ us4v cvt4(float4 v) {
    us4v r;
    r.x = f2bf(v.x); r.y = f2bf(v.y); r.z = f2bf(v.z); r.w = f2bf(v.w);
    return r;
}

// async global->LDS, 16 B per lane; LDS dest = wave-uniform base + lane*16
__device__ __forceinline__ void gl16(const unsigned short* g, unsigned short* l) {
    __builtin_amdgcn_global_load_lds(
        (const __attribute__((address_space(1))) unsigned*)g,
        (__attribute__((address_space(3))) unsigned*)l, 16, 0, 0);
}

// ---------------------------------------------------------------------------
// Kernel 0: fp32 -> bf16 convert (one float4 per thread)
// ---------------------------------------------------------------------------
__global__ __launch_bounds__(256)
void cvt_bf16(const float* __restrict__ src, unsigned short* __restrict__ dst,
              int n4) {
    const int i = blockIdx.x * 256 + threadIdx.x;
    if (i < n4) {
        float4 v = ((const float4*)src)[i];
        ((us4v*)dst)[i] = cvt4(v);
    }
}

// ---------------------------------------------------------------------------
// Kernel 1: qkv = xb @ winb^T + b_in -> q (x0.125), k in (B,H,N,D) bf16,
//           V written directly transposed as vbT (B,H,D,N) bf16.
// Triple-buffered counted-vmcnt pipeline (prefetch distance 2).
// ---------------------------------------------------------------------------
__global__ __launch_bounds__(256, 3)
void qkv_gemm(const unsigned short* __restrict__ xb,   // (8192,1024) bf16
              const unsigned short* __restrict__ wb,   // (3072,1024) bf16
              const float* __restrict__ bias,
              unsigned short* __restrict__ qb, unsigned short* __restrict__ kb,
              unsigned short* __restrict__ vbT)
{
    __shared__ unsigned short lsa[3][128 * 32];
    __shared__ unsigned short lsb[3][128 * 32];
    const int tid  = threadIdx.x;
    const int wave = tid >> 6, lane = tid & 63;
    const int quad = lane >> 4, l15 = lane & 15;
    const int rch = (quad ^ ((l15 >> 1) & 3)) * 8;   // swizzled read chunk
    const int m0 = blockIdx.x * 128, n0 = blockIdx.y * 128;
    const int wm = (wave & 1) * 64, wn = (wave >> 1) * 64;

    const int srow = wave * 32 + (lane >> 2);
    const int scol = ((lane & 3) ^ ((lane >> 3) & 3)) * 8;   // swizzled stage
    const unsigned short* ga = xb + (size_t)(m0 + srow) * 1024 + scol;
    const unsigned short* gb = wb + (size_t)(n0 + srow) * 1024 + scol;
    const int so0 = (wave * 32) * 32;          // stage offsets within a buffer
    const int so1 = (wave * 32 + 16) * 32;

    f32x4 acc[4][4];
#pragma unroll
    for (int i = 0; i < 4; ++i)
#pragma unroll
        for (int j = 0; j < 4; ++j) acc[i][j] = (f32x4){0.f, 0.f, 0.f, 0.f};

    // prologue: stage kt=0 -> buf0, kt=1 -> buf1 (no wait; loop handles it)
    gl16(ga, &lsa[0][so0]);
    gl16(ga + 16 * 1024, &lsa[0][so1]);
    gl16(gb, &lsb[0][so0]);
    gl16(gb + 16 * 1024, &lsb[0][so1]);
    gl16(ga + 32, &lsa[1][so0]);
    gl16(ga + 16 * 1024 + 32, &lsa[1][so1]);
    gl16(gb + 32, &lsb[1][so0]);
    gl16(gb + 16 * 1024 + 32, &lsb[1][so1]);

    for (int kt = 0; kt < 32; ++kt) {
        const int cb = kt % 3;
        if (kt < 30) {                         // stage kt+2 (distance 2)
            const int k0 = (kt + 2) * 32;
            const int sb = (kt + 2) % 3;
            gl16(ga + k0, &lsa[sb][so0]);
            gl16(ga + 16 * 1024 + k0, &lsa[sb][so1]);
            gl16(gb + k0, &lsb[sb][so0]);
            gl16(gb + 16 * 1024 + k0, &lsb[sb][so1]);
            asm volatile("s_waitcnt vmcnt(8)" ::: "memory");  // tile kt landed
        } else if (kt == 30) {
            asm volatile("s_waitcnt vmcnt(4)" ::: "memory");
        } else {
            asm volatile("s_waitcnt vmcnt(0)" ::: "memory");
        }
        __builtin_amdgcn_s_barrier();

        const unsigned short* pa = lsa[cb];
        const unsigned short* pb = lsb[cb];
        bf16x8 af[4], bfr[4];
#pragma unroll
        for (int i = 0; i < 4; ++i)
            af[i] = *(const bf16x8*)&pa[(wm + i * 16 + l15) * 32 + rch];
#pragma unroll
        for (int j = 0; j < 4; ++j)
            bfr[j] = *(const bf16x8*)&pb[(wn + j * 16 + l15) * 32 + rch];
#pragma unroll
        for (int i = 0; i < 4; ++i)
#pragma unroll
            for (int j = 0; j < 4; ++j)
                acc[i][j] = MFMA16(af[i], bfr[j], acc[i][j], 0, 0, 0);

        asm volatile("s_waitcnt lgkmcnt(0)" ::: "memory");  // reads done
        __builtin_amdgcn_sched_barrier(0);
        __builtin_amdgcn_s_barrier();          // protect buf reuse (kt+3)
    }

    const int which = n0 >> 10;
    if (which == 2) {
        // V: write transposed (bh, d, seq); (i,r) axis is seq -> pack 4 bf16.
#pragma unroll
        for (int j = 0; j < 4; ++j) {
            const int n = n0 + wn + j * 16 + l15;
            const int c = n & 1023;
            const int h = c >> 6, d = c & 63;
            const float bv = bias[n];
#pragma unroll
            for (int i = 0; i < 4; ++i) {
                const int m = m0 + wm + i * 16 + quad * 4;   // r=0 row
                const int b = m >> 10, s = m & 1023;
                us4v pk;
#pragma unroll
                for (int r = 0; r < 4; ++r) pk[r] = f2bf(acc[i][j][r] + bv);
                *(us4v*)&vbT[(size_t)((b * 16 + h) * 64 + d) * 1024 + s] = pk;
            }
        }
    } else {
        unsigned short* __restrict__ dst = (which == 0) ? qb : kb;
        const float sc = (which == 0) ? 0.125f : 1.0f;   // q / sqrt(64)
#pragma unroll
        for (int j = 0; j < 4; ++j) {
            const int n = n0 + wn + j * 16 + l15;
            const int c = n & 1023;
            const int h = c >> 6, d = c & 63;
            const float bv = bias[n];
#pragma unroll
            for (int i = 0; i < 4; ++i)
#pragma unroll
                for (int r = 0; r < 4; ++r) {
                    const int m = m0 + wm + i * 16 + quad * 4 + r;
                    const int b = m >> 10, s = m & 1023;
                    const float v = (acc[i][j][r] + bv) * sc;
                    dst[(size_t)((b * 16 + h) * 1024 + s) * 64 + d] = f2bf(v);
                }
        }
    }
}

// ---------------------------------------------------------------------------
// Kernel 2: flash attention, swapped-QK^T, QBLK=128, counted-vmcnt 2-phase.
//   K/V dbuf via gl16; mask reg-dbuf issued after gl16 (order pinned);
//   end-of-iter: lgkmcnt(0) -> vmcnt(8) -> RAW s_barrier (mask loads ride
//   across). lsp: per-wave per-group swizzled 16x64 (parallel, no serial
//   reuse). LDS 48KB -> 3 blocks/CU. Grid 1024, XCD-swizzled.
// ---------------------------------------------------------------------------
__global__ __launch_bounds__(256, 3)
void attn_kernel(const unsigned short* __restrict__ qb,
                 const unsigned short* __restrict__ kb,
                 const unsigned short* __restrict__ vbT,  // (bh, d, n)
                 const float* __restrict__ mask,
                 unsigned short* __restrict__ ob)   // (B, N, C) bf16
{
    __shared__ unsigned short lsk[2][2][64 * 32];     // [buf][d-half][seq*32]
    __shared__ unsigned short lsv[2][2][64 * 32];     // [buf][key-half][d*32]
    __shared__ unsigned short lsp[4][2][16 * 64];     // [wave][grp], swizzled
    const int tid  = threadIdx.x;
    const int wave = tid >> 6, lane = tid & 63;
    const int quad = lane >> 4, l15 = lane & 15;
    const int rch = (quad ^ ((l15 >> 1) & 3)) * 8;   // swizzled read chunk
    const int swz = (l15 & 7) << 3;                  // P granule swizzle
    const int p  = blockIdx.x;
    const int lg = (p & 7) * 128 + (p >> 3);         // XCD swizzle (bijective)
    const int bh = lg >> 3;                          // b*16+h
    const int q0 = (lg & 7) * 128;
    const int b = bh >> 4, h = bh & 15;

    const unsigned short* __restrict__ kbase = kb + (size_t)bh * 65536;
    const unsigned short* __restrict__ vtb  = vbT + (size_t)bh * 65536;

    const int scol = ((lane & 3) ^ ((lane >> 3) & 3)) * 8;   // swizzled stage
    const unsigned short* gk = kbase + (size_t)(wave * 16 + (lane >> 2)) * 64
                                     + scol;
    const unsigned short* gv = vtb + (size_t)(wave * 16 + (lane >> 2)) * 1024
                                   + scol;
    const int so = (wave * 16) * 32;             // stage offset within a half

    // Q fragments, 2 groups (B-operand: n = l15 = q, k = quad*8+j = d)
    bf16x8 bq[2][2];
#pragma unroll
    for (int g = 0; g < 2; ++g) {
        const unsigned short* qrow =
            qb + (size_t)(bh * 1024 + q0 + wave * 32 + g * 16 + l15) * 64;
        bq[g][0] = *(const bf16x8*)(qrow + quad * 8);
        bq[g][1] = *(const bf16x8*)(qrow + 32 + quad * 8);
    }

    float lsum[2] = {0.f, 0.f};
    f32x4 oacc[2][4];              // [grp][nt]: O[q=l15][d=nt*16+quad*4+r]
#pragma unroll
    for (int g = 0; g < 2; ++g)
#pragma unroll
        for (int nt = 0; nt < 4; ++nt) oacc[g][nt] = (f32x4){0.f, 0.f, 0.f, 0.f};

    const float* __restrict__ mrow0 =
        mask + (size_t)(q0 + wave * 32 + l15) * 1024;
    const float* __restrict__ mrow1 = mrow0 + 16 * 1024;

    // prologue: stage tile 0 -> buf 0, mask tile 0 -> mcur; one full drain
    gl16(gk, &lsk[0][0][so]);
    gl16(gk + 32, &lsk[0][1][so]);
    gl16(gv, &lsv[0][0][so]);
    gl16(gv + 32, &lsv[0][1][so]);
    float4 mcur[2][4];
#pragma unroll
    for (int nt = 0; nt < 4; ++nt) {
        mcur[0][nt] = *(const float4*)&mrow0[nt * 16 + quad * 4];
        mcur[1][nt] = *(const float4*)&mrow1[nt * 16 + quad * 4];
    }
    __syncthreads();

    int buf = 0;
    for (int kt = 0; kt < 16; ++kt) {
        float4 mnext[2][4];
        if (kt < 15) {
            // stage next K/V tile FIRST (these are what vmcnt(8) must cover)
            gl16(gk + (size_t)(kt + 1) * 4096, &lsk[buf ^ 1][0][so]);
            gl16(gk + (size_t)(kt + 1) * 4096 + 32, &lsk[buf ^ 1][1][so]);
            gl16(gv + (size_t)(kt + 1) * 64, &lsv[buf ^ 1][0][so]);
            gl16(gv + (size_t)(kt + 1) * 64 + 32, &lsv[buf ^ 1][1][so]);
            __builtin_amdgcn_sched_barrier(0);   // pin: gl16 older than masks
            // mask t+1 -> registers; ride across the end-of-iter barrier
#pragma unroll
            for (int nt = 0; nt < 4; ++nt) {
                mnext[0][nt] =
                    *(const float4*)&mrow0[(kt + 1) * 64 + nt * 16 + quad * 4];
                mnext[1][nt] =
                    *(const float4*)&mrow1[(kt + 1) * 64 + nt * 16 + quad * 4];
            }
        }

        // S^T = K Q^T  (C-layout: row=key=quad*4+r, col=q=l15), both groups
        const unsigned short* rk0 = lsk[buf][0];
        const unsigned short* rk1 = lsk[buf][1];
        f32x4 s[2][4];
        __builtin_amdgcn_s_setprio(1);
#pragma unroll
        for (int nt = 0; nt < 4; ++nt) {
            const bf16x8 k0 = *(const bf16x8*)&rk0[(nt * 16 + l15) * 32 + rch];
            const bf16x8 k1 = *(const bf16x8*)&rk1[(nt * 16 + l15) * 32 + rch];
            s[0][nt] = MFMA16(k0, bq[0][0], (f32x4){0.f, 0.f, 0.f, 0.f}, 0, 0, 0);
            s[0][nt] = MFMA16(k1, bq[0][1], s[0][nt], 0, 0, 0);
            s[1][nt] = MFMA16(k0, bq[1][0], (f32x4){0.f, 0.f, 0.f, 0.f}, 0, 0, 0);
            s[1][nt] = MFMA16(k1, bq[1][1], s[1][nt], 0, 0, 0);
        }
        __builtin_amdgcn_s_setprio(0);

        // p = exp(s + mask_regs) -> per-group swizzled lsp (parallel bufs)
        unsigned short* lp0 = lsp[wave][0];
        unsigned short* lp1 = lsp[wave][1];
#pragma unroll
        for (int nt = 0; nt < 4; ++nt) {
            us4v pk0, pk1;
#pragma unroll
            for (int r = 0; r < 4; ++r) {
                const float pe0 =
                    __expf(s[0][nt][r] + ((const float*)&mcur[0][nt])[r]);
                const float pe1 =
                    __expf(s[1][nt][r] + ((const float*)&mcur[1][nt])[r]);
                lsum[0] += pe0;
                lsum[1] += pe1;
                pk0[r] = f2bf(pe0);
                pk1[r] = f2bf(pe1);
            }
            const int off = (nt * 16 + quad * 4) ^ swz;
            *(us4v*)&lp0[(l15 << 6) + off] = pk0;
            *(us4v*)&lp1[(l15 << 6) + off] = pk1;
        }
        bf16x8 pb0[2], pb1[2];
        pb0[0] = *(const bf16x8*)&lp0[(l15 << 6) + ((quad * 8) ^ swz)];
        pb0[1] = *(const bf16x8*)&lp0[(l15 << 6) + ((32 + quad * 8) ^ swz)];
        pb1[0] = *(const bf16x8*)&lp1[(l15 << 6) + ((quad * 8) ^ swz)];
        pb1[1] = *(const bf16x8*)&lp1[(l15 << 6) + ((32 + quad * 8) ^ swz)];

        // O += P V via O = (V^T as A) x (P^T as B): C row=d, col=q
        const unsigned short* rv0 = lsv[buf][0];
        const unsigned short* rv1 = lsv[buf][1];
        __builtin_amdgcn_s_setprio(1);
#pragma unroll
        for (int nt = 0; nt < 4; ++nt) {
            const bf16x8 v0 = *(const bf16x8*)&rv0[(nt * 16 + l15) * 32 + rch];
            const bf16x8 v1 = *(const bf16x8*)&rv1[(nt * 16 + l15) * 32 + rch];
            oacc[0][nt] = MFMA16(v0, pb0[0], oacc[0][nt], 0, 0, 0);
            oacc[0][nt] = MFMA16(v1, pb0[1], oacc[0][nt], 0, 0, 0);
            oacc[1][nt] = MFMA16(v0, pb1[0], oacc[1][nt], 0, 0, 0);
            oacc[1][nt] = MFMA16(v1, pb1[1], oacc[1][nt], 0, 0, 0);
        }
        __builtin_amdgcn_s_setprio(0);

        if (kt < 15) {
            asm volatile("s_waitcnt lgkmcnt(0)" ::: "memory"); // LDS reads done
            __builtin_amdgcn_sched_barrier(0);
            asm volatile("s_waitcnt vmcnt(8)" ::: "memory");   // gl16(t+1) in
            __builtin_amdgcn_s_barrier();      // raw: masks stay in flight
#pragma unroll
            for (int g = 0; g < 2; ++g)
#pragma unroll
                for (int nt = 0; nt < 4; ++nt) mcur[g][nt] = mnext[g][nt];
        }
        buf ^= 1;
    }

    // row-sum: partial sums per-quad; reduce across lane bits 4,5
#pragma unroll
    for (int g = 0; g < 2; ++g) {
        lsum[g] += __shfl_xor(lsum[g], 16, 64);
        lsum[g] += __shfl_xor(lsum[g], 32, 64);
    }
#pragma unroll
    for (int g = 0; g < 2; ++g) {
        const float inv = 1.0f / lsum[g];
        unsigned short* orow =
            ob + (size_t)(b * 1024 + q0 + wave * 32 + g * 16 + l15) * 1024
               + h * 64;
#pragma unroll
        for (int nt = 0; nt < 4; ++nt) {
            us4v o;
#pragma unroll
            for (int r = 0; r < 4; ++r) o[r] = f2bf(oacc[g][nt][r] * inv);
            *(us4v*)&orow[nt * 16 + quad * 4] = o;
        }
    }
}

// ---------------------------------------------------------------------------
// Kernel 3: out = ob(bf16) @ woutb^T + out_b, fp32 to d_out.
// Triple-buffered counted-vmcnt pipeline (prefetch distance 2).
// ---------------------------------------------------------------------------
__global__ __launch_bounds__(256, 3)
void out_gemm(const unsigned short* __restrict__ a,   // (8192,1024) bf16
              const unsigned short* __restrict__ wb,  // (1024,1024) bf16
              const float* __restrict__ bias, float* __restrict__ out)
{
    __shared__ unsigned short lsa[3][128 * 32];
    __shared__ unsigned short lsb[3][128 * 32];
    const int tid  = threadIdx.x;
    const int wave = tid >> 6, lane = tid & 63;
    const int quad = lane >> 4, l15 = lane & 15;
    const int rch = (quad ^ ((l15 >> 1) & 3)) * 8;
    const int m0 = blockIdx.x * 128, n0 = blockIdx.y * 128;
    const int wm = (wave & 1) * 64, wn = (wave >> 1) * 64;

    const int srow = wave * 32 + (lane >> 2);
    const int scol = ((lane & 3) ^ ((lane >> 3) & 3)) * 8;
    const unsigned short* ga = a + (size_t)(m0 + srow) * 1024 + scol;
    const unsigned short* gb = wb + (size_t)(n0 + srow) * 1024 + scol;
    const int so0 = (wave * 32) * 32;
    const int so1 = (wave * 32 + 16) * 32;

    f32x4 acc[4][4];
#pragma unroll
    for (int i = 0; i < 4; ++i)
#pragma unroll
        for (int j = 0; j < 4; ++j) acc[i][j] = (f32x4){0.f, 0.f, 0.f, 0.f};

    gl16(ga, &lsa[0][so0]);
    gl16(ga + 16 * 1024, &lsa[0][so1]);
    gl16(gb, &lsb[0][so0]);
    gl16(gb + 16 * 1024, &lsb[0][so1]);
    gl16(ga + 32, &lsa[1][so0]);
    gl16(ga + 16 * 1024 + 32, &lsa[1][so1]);
    gl16(gb + 32, &lsb[1][so0]);
    gl16(gb + 16 * 1024 + 32, &lsb[1][so1]);

    for (int kt = 0; kt < 32; ++kt) {
        const int cb = kt % 3;
        if (kt < 30) {
            const int k0 = (kt + 2) * 32;
            const int sb = (kt + 2) % 3;
            gl16(ga + k0, &lsa[sb][so0]);
            gl16(ga + 16 * 1024 + k0, &lsa[sb][so1]);
            gl16(gb + k0, &lsb[sb][so0]);
            gl16(gb + 16 * 1024 + k0, &lsb[sb][so1]);
            asm volatile("s_waitcnt vmcnt(8)" ::: "memory");
        } else if (kt == 30) {
            asm volatile("s_waitcnt vmcnt(4)" ::: "memory");
        } else {
            asm volatile("s_waitcnt vmcnt(0)" ::: "memory");
        }
        __builtin_amdgcn_s_barrier();

        const unsigned short* pa = lsa[cb];
        const unsigned short* pb = lsb[cb];
        bf16x8 af[4], bfr[4];
#pragma unroll
        for (int i = 0; i < 4; ++i)
            af[i] = *(const bf16x8*)&pa[(wm + i * 16 + l15) * 32 + rch];
#pragma unroll
        for (int j = 0; j < 4; ++j)
            bfr[j] = *(const bf16x8*)&pb[(wn + j * 16 + l15) * 32 + rch];
#pragma unroll
        for (int i = 0; i < 4; ++i)
#pragma unroll
            for (int j = 0; j < 4; ++j)
                acc[i][j] = MFMA16(af[i], bfr[j], acc[i][j], 0, 0, 0);

        asm volatile("s_waitcnt lgkmcnt(0)" ::: "memory");
        __builtin_amdgcn_sched_barrier(0);
        __builtin_amdgcn_s_barrier();
    }

#pragma unroll
    for (int j = 0; j < 4; ++j) {
        const int n = n0 + wn + j * 16 + l15;
        const float bv = bias[n];
#pragma unroll
        for (int i = 0; i < 4; ++i)
#pragma unroll
            for (int r = 0; r < 4; ++r) {
                const int m = m0 + wm + i * 16 + quad * 4 + r;
                out[(size_t)m * 1024 + n] = acc[i][j][r] + bv;
            }
    }
}

// ---------------------------------------------------------------------------
extern "C" void kernel_launch(void* const* d_in, const int* in_sizes, int n_in,
                              void* d_out, int out_size, void* d_ws, size_t ws_size,
                              hipStream_t stream) {
    const float* x    = (const float*)d_in[0];   // (8, 1024, 1024)
    const float* mask = (const float*)d_in[1];   // (1024, 1024)
    const float* win  = (const float*)d_in[2];   // (3072, 1024)
    const float* bin  = (const float*)d_in[3];   // (3072)
    const float* wout = (const float*)d_in[4];   // (1024, 1024)
    const float* bout = (const float*)d_in[5];   // (1024)
    float* out = (float*)d_out;                  // (8, 1024, 1024)

    char* ws = (char*)d_ws;
    unsigned short* xb = (unsigned short*)(ws);
    unsigned short* ob = (unsigned short*)(ws);                       // overlays xb
    unsigned short* qb = (unsigned short*)(ws + (size_t)(16 << 20));
    unsigned short* kb = (unsigned short*)(ws + (size_t)(32 << 20));
    unsigned short* vbT = (unsigned short*)(ws + (size_t)(48 << 20));
    unsigned short* winb  = (unsigned short*)d_out;                   // [0, 6M)
    unsigned short* woutb = qb;   // overlays qb AFTER attn (qb dead) — no race

    cvt_bf16<<<dim3(8192), 256, 0, stream>>>(x, xb, 8 * 1024 * 1024 / 4);
    cvt_bf16<<<dim3(3072), 256, 0, stream>>>(win, winb, 3 * 1024 * 1024 / 4);
    qkv_gemm<<<dim3(64, 24), 256, 0, stream>>>(xb, winb, bin, qb, kb, vbT);
    attn_kernel<<<dim3(1024), 256, 0, stream>>>(qb, kb, vbT, mask, ob);
    cvt_bf16<<<dim3(1024), 256, 0, stream>>>(wout, woutb, 1024 * 1024 / 4);
    out_gemm<<<dim3(64, 8), 256, 0, stream>>>(ob, woutb, bout, out);
}